// Round 6
// baseline (1396.462 us; speedup 1.0000x reference)
//
#include <hip/hip_runtime.h>

#define N_NODES 100000
#define N_EDGES 1600000
#define IN_F 256
#define OUT_F 128

#define NBUCK 1563              // ceil(N_NODES / 64)
#define SUB 8
#define NCELL (NBUCK * SUB)     // 12504
#define CELL_CAP 256            // cell mean=128, sd=11.3
#define SPILL_CAP 65536
#define ACC_STRIDE 136          // 64 rows x 136 f32: bank aliasing <=2-way (free)

typedef __attribute__((ext_vector_type(8))) short bf16x8;
typedef __attribute__((ext_vector_type(4))) float f32x4;

static __device__ __forceinline__ unsigned f2bf_u(float f) {
    unsigned u = __float_as_uint(f);
    return (u + 0x7FFFu + ((u >> 16) & 1u)) >> 16;      // RNE; inputs finite
}
static __device__ __forceinline__ float bf2f(short s) {
    return __uint_as_float(((unsigned)(unsigned short)s) << 16);
}

// ---------- prep: zero counters (blocks 0..48) + wt fragment-major (blocks 49..64) ----------
// wtf[(ks*8+nt)*512 + lane*8 + j] = bf16(w[(ks*32+q*8+j)*128 + nt*16+m]), lane=(q<<4)|m
__global__ __launch_bounds__(256) void prep_kernel(int* __restrict__ cnt,
                                                   const float* __restrict__ w,
                                                   unsigned short* __restrict__ wtf) {
    const int bid = blockIdx.x;
    if (bid < 49) {
        int i = bid * 256 + threadIdx.x;
        if (i < NCELL + 1) cnt[i] = 0;                   // cnt[NCELL] = spill counter
    } else {
        int id = (bid - 49) * 256 + threadIdx.x;         // 0..4095
        int f = id >> 6, lane = id & 63;
        int ks = f >> 3, nt = f & 7;
        int m = lane & 15, q = lane >> 4;
        int row = nt * 16 + m;
        int col0 = ks * 32 + q * 8;
        unsigned short* o = wtf + (size_t)f * 512 + lane * 8;
        #pragma unroll
        for (int j = 0; j < 8; ++j)
            o[j] = (unsigned short)f2bf_u(w[(size_t)(col0 + j) * OUT_F + row]);
    }
}

// ---------- fused partition + GEMM ----------
// grid = 5*NBUCK = 7815. blockIdx%5==4 -> gemm (gid=blockIdx/5, 1563 blocks);
// else -> partition (pid = (blockIdx/5)*4 + blockIdx%5, 6252 blocks).
// Partition waves are mem-latency-bound (VALU 0.8%), gemm waves MFMA/LDS-bound:
// co-resident on a CU they overlap (m114: time ~ max, not sum).
__global__ __launch_bounds__(256) void fused_kernel(const int* __restrict__ edge_src,
                                                    const int* __restrict__ edge_dst,
                                                    const float* __restrict__ edge_weight,
                                                    int* __restrict__ cnt,
                                                    int2* __restrict__ part,
                                                    int4* __restrict__ spill,
                                                    const float* __restrict__ x,
                                                    const unsigned short* __restrict__ wtf,
                                                    unsigned short* __restrict__ hbp) {
    __shared__ unsigned short xs[64][264];               // gemm role only (33.8 KB)
    const int t = threadIdx.x;
    const int bid = blockIdx.x;

    if (bid % 5 != 4) {
        // ---- partition role ----
        int pid = (bid / 5) * 4 + (bid % 5);
        int e = pid * 256 + t;
        if (e < N_EDGES) {
            int d = edge_dst[e];
            int cell = (d >> 6) * SUB + (bid & 7);
            int pos = atomicAdd(&cnt[cell], 1);
            if (pos < CELL_CAP) {
                part[(size_t)cell * CELL_CAP + pos] =
                    make_int2(edge_src[e] | ((d & 63) << 24), __float_as_int(edge_weight[e]));
            } else {                                      // statistically unreachable
                int sp = atomicAdd(&cnt[NCELL], 1);
                if (sp < SPILL_CAP)
                    spill[sp] = make_int4(edge_src[e], d, __float_as_int(edge_weight[e]), 0);
            }
        }
        return;
    }

    // ---- gemm role: h = bf16(x) @ bf16(w), output in permuted layout ----
    // hbp[node][m*8+nt] = h[node][nt*16+m]
    const int gid = bid / 5;
    const int row0 = gid * 64;

    const float4* x4 = (const float4*)x;
    #pragma unroll
    for (int i = 0; i < 16; ++i) {
        int idx = t + i * 256;
        int r = idx >> 6, c4 = idx & 63;
        int rg = row0 + r; if (rg >= N_NODES) rg = N_NODES - 1;
        float4 v = x4[(size_t)rg * 64 + c4];
        unsigned u0 = f2bf_u(v.x) | (f2bf_u(v.y) << 16);
        unsigned u1 = f2bf_u(v.z) | (f2bf_u(v.w) << 16);
        *(uint2*)&xs[r][c4 * 4] = make_uint2(u0, u1);
    }
    __syncthreads();

    const int wave = t >> 6, lane = t & 63;
    const int m = lane & 15, quad = lane >> 4;

    bf16x8 af[8];
    #pragma unroll
    for (int ks = 0; ks < 8; ++ks)
        af[ks] = *(const bf16x8*)&xs[wave * 16 + m][ks * 32 + quad * 8];

    f32x4 acc[8];
    #pragma unroll
    for (int nt = 0; nt < 8; ++nt) acc[nt] = (f32x4){0.f, 0.f, 0.f, 0.f};

    const bf16x8* wf = (const bf16x8*)wtf;
    #pragma unroll
    for (int ks = 0; ks < 8; ++ks) {
        #pragma unroll
        for (int nt = 0; nt < 8; ++nt) {
            bf16x8 bf = wf[(size_t)(ks * 8 + nt) * 64 + lane];
            acc[nt] = __builtin_amdgcn_mfma_f32_16x16x32_bf16(af[ks], bf, acc[nt], 0, 0, 0);
        }
    }

    const int tile_base = row0 + wave * 16;
    #pragma unroll
    for (int r = 0; r < 4; ++r) {
        int orow = tile_base + quad * 4 + r;             // C/D: col=lane&15, row=quad*4+reg
        if (orow < N_NODES) {
            bf16x8 o;
            #pragma unroll
            for (int nt = 0; nt < 8; ++nt)
                o[nt] = (short)f2bf_u(acc[nt][r]);
            *(bf16x8*)(hbp + (size_t)orow * OUT_F + m * 8) = o;   // 16B coalesced
        }
    }
}

// ---------- SpMM: fp32 LDS accumulator, ds-atomic accumulate, no list build ----------
// Block = 64-node bucket. acc[n][f] at n*136+f (bank aliasing <=2-way).
// 16-lane group g handles entry i (broadcast 8B read); lane j in group covers
// features {k*16+j} via hbp[src][j*8..j*8+7] (16B load).
__global__ __launch_bounds__(256) void spmm_kernel(const unsigned short* __restrict__ hbp,
                                                   const int* __restrict__ cnt,
                                                   const int2* __restrict__ part,
                                                   const int4* __restrict__ spill,
                                                   const float* __restrict__ b,
                                                   float* __restrict__ out) {
    __shared__ float acc[64 * ACC_STRIDE];               // 34.8 KB
    const int t = threadIdx.x;
    const int gi = t >> 4;                               // 0..15 entry-group
    const int j  = t & 15;                               // feature slot

    float4 z4 = make_float4(0.f, 0.f, 0.f, 0.f);
    for (int i = t; i < 64 * ACC_STRIDE / 4; i += 256)
        ((float4*)acc)[i] = z4;
    __syncthreads();

    #pragma unroll
    for (int sub = 0; sub < SUB; ++sub) {
        const int cell = blockIdx.x * SUB + sub;
        int c = cnt[cell]; if (c > CELL_CAP) c = CELL_CAP;
        const int2* cp = part + (size_t)cell * CELL_CAP;
        for (int i = gi; i < c; i += 16) {
            const int2 en = cp[i];                       // 16 lanes same addr: broadcast
            const int n   = ((unsigned)en.x) >> 24;
            const int src = en.x & 0xFFFFFF;
            const float wgt = __int_as_float(en.y);
            const bf16x8 hv = *(const bf16x8*)(hbp + (size_t)src * OUT_F + j * 8);
            float* ap = acc + n * ACC_STRIDE + j;
            #pragma unroll
            for (int k = 0; k < 8; ++k)
                atomicAdd(ap + k * 16, wgt * bf2f(hv[k]));   // ds_add_f32
        }
    }
    __syncthreads();

    // spill fixup into LDS (normally 0 entries: one scalar load + skip)
    int spn = cnt[NCELL]; if (spn > SPILL_CAP) spn = SPILL_CAP;
    for (int i = t; i < spn; i += 256) {
        int4 sp = spill[i];
        if ((sp.y >> 6) == (int)blockIdx.x) {
            int n = sp.y & 63;
            float wgt = __int_as_float(sp.z);
            for (int f = 0; f < OUT_F; ++f) {
                // h[src][f] lives at hbp[src][(f&15)*8 + (f>>4)]
                float hv = bf2f((short)hbp[(size_t)sp.x * OUT_F + (f & 15) * 8 + (f >> 4)]);
                atomicAdd(acc + n * ACC_STRIDE + f, wgt * hv);
            }
        }
    }
    if (spn) __syncthreads();

    // epilogue: out[node] = acc[n] + b
    const float4* b4 = (const float4*)b;
    const float4 bb0 = b4[j * 2];
    const float4 bb1 = b4[j * 2 + 1];
    #pragma unroll
    for (int g = 0; g < 4; ++g) {
        const int n = g * 16 + gi;
        const int node = blockIdx.x * 64 + n;
        if (node >= N_NODES) continue;
        float4 v0 = *(float4*)(acc + n * ACC_STRIDE + j * 8);
        float4 v1 = *(float4*)(acc + n * ACC_STRIDE + j * 8 + 4);
        v0.x += bb0.x; v0.y += bb0.y; v0.z += bb0.z; v0.w += bb0.w;
        v1.x += bb1.x; v1.y += bb1.y; v1.z += bb1.z; v1.w += bb1.w;
        float4* o4 = (float4*)(out + (size_t)node * OUT_F + j * 8);
        o4[0] = v0;
        o4[1] = v1;
    }
}

extern "C" void kernel_launch(void* const* d_in, const int* in_sizes, int n_in,
                              void* d_out, int out_size, void* d_ws, size_t ws_size,
                              hipStream_t stream) {
    const float* x           = (const float*)d_in[0];
    const int*   edge_src    = (const int*)d_in[1];
    const int*   edge_dst    = (const int*)d_in[2];
    const float* edge_weight = (const float*)d_in[3];
    const float* w           = (const float*)d_in[4];
    const float* b           = (const float*)d_in[5];
    float* out = (float*)d_out;

    // workspace layout (16B-aligned), total ~52.4 MB
    char* ws = (char*)d_ws;
    size_t off = 0;
    unsigned short* hbp = (unsigned short*)(ws + off); off += (size_t)N_NODES * OUT_F * 2;   // 25.6 MB
    unsigned short* wtf = (unsigned short*)(ws + off); off += (size_t)IN_F * OUT_F * 2;      // 64 KB
    int* cnt = (int*)(ws + off);     off += ((size_t)NCELL + 4) * 4;                         // 50 KB
    off = (off + 15) & ~(size_t)15;
    int4* spill = (int4*)(ws + off); off += (size_t)SPILL_CAP * 16;                          // 1 MB
    int2* part = (int2*)(ws + off);  off += (size_t)NCELL * CELL_CAP * 8;                    // 25.6 MB

    prep_kernel<<<65, 256, 0, stream>>>(cnt, w, wtf);
    fused_kernel<<<5 * NBUCK, 256, 0, stream>>>(edge_src, edge_dst, edge_weight,
                                                cnt, part, spill, x, wtf, hbp);
    spmm_kernel<<<NBUCK, 256, 0, stream>>>(hbp, cnt, part, spill, b, out);
}